// Round 13
// baseline (212.715 us; speedup 1.0000x reference)
//
#include <hip/hip_runtime.h>

// ---------------------------------------------------------------------------
// PEPS 4x5, D=4, P=2, depth-5 gate sweeps, 64-point gather.
// ONE persistent kernel (plain launch), 13 fence-free tree barriers:
//   P1 cols -> P2 {M34T || M01} -> P3 t012 -> P4 psi0 -> 5x(G-P1, G-P2).
//
// COHERENCE MODEL (r6..r12 lessons, final form): dispatch-end = wbL2
// (write-back, NO invalidate). The harness's ws-zeroing fill leaves CLEAN
// ZERO lines in L2. Coherent (sc0 sc1) accesses bypass them harmlessly
// (clean lines never write back), but ANY cached ws read deterministically
// returns a stale zero. => every ws access is coherent: stores via sc0 sc1
// asm; loads via sc0 sc1 asm x4 or __hip_atomic_load AGENT. Cached reads
// ONLY for true inputs (peps/x/gate).
// r13 = r7 (200.2us, best verified) + agl() on M01's col0/col1 reads —
// r7's ONLY cached ws reads (source of its deterministic 4.4e20 absmax).
// Everything else byte-identical to r7. (r10-r12 x4-setup arc abandoned:
// deterministic bug in its coh_gemm2 context, 3 audits clean, not worth
// further rounds.)
// Hot streaming loops are source-level software-pipelined (32-wide
// double-buffered chunks, fully unrolled -> static reg indices).
// Gate layout: psi idx = c3<<16 | c4<<12 | c0<<8 | c1<<4 | c2.
// ---------------------------------------------------------------------------

#define PAD(i) ((i) + (((i) >> 4) << 2))   // +4 floats per 16 -> LDS bank spread
#define PIDX(i,j,p,u,d,l,r) (((((((i)*5+(j))*2+(p))*4+(u))*4+(d))*4+(l))*4+(r))

typedef float v4f __attribute__((ext_vector_type(4)));

// workspace float offsets
static constexpr int COL0  = 0;                    // [16][256]
static constexpr int COL1  = 4096;                 // [16][256][256]
static constexpr int COL2  = COL1 + 1048576;
static constexpr int COL3  = COL2 + 1048576;
static constexpr int COL4  = COL3 + 1048576;       // [16][256]
static constexpr int M01TO = COL4 + 4096;          // [c01=256][R2=256]
static constexpr int M34TO = M01TO + 65536;        // [L3=256][c34=256]
static constexpr int T12TO = M34TO + 65536;        // [c2=16][c01=256][R3=256]
static constexpr int PSIO  = T12TO + 1048576;      // [2^20] gate layout
static constexpr int CNTO  = PSIO + 1048576;       // barrier tree: 1088 ints

// ---------------- coherent-point access ------------------------------------
__device__ __forceinline__ float agl(const float* p) {      // coherent load
  return __hip_atomic_load(p, __ATOMIC_RELAXED, __HIP_MEMORY_SCOPE_AGENT);
}
__device__ __forceinline__ void cohload2(const float* p0, const float* p1,
                                         v4f& a, v4f& b) {
  asm volatile(
      "global_load_dwordx4 %0, %2, off sc0 sc1\n\t"
      "global_load_dwordx4 %1, %3, off sc0 sc1\n\t"
      "s_waitcnt vmcnt(0)"
      : "=&v"(a), "=&v"(b)
      : "v"(p0), "v"(p1)
      : "memory");
}
__device__ __forceinline__ void cohstore(float* p, v4f v) {
  asm volatile("global_store_dwordx4 %0, %1, off sc0 sc1"
               :
               : "v"(p), "v"(v)
               : "memory");
}
__device__ __forceinline__ void cohstore1(float* p, float v) {
  asm volatile("global_store_dword %0, %1, off sc0 sc1"
               :
               : "v"(p), "v"(v)
               : "memory");
}
__device__ __forceinline__ void vmdrain() {
  asm volatile("s_waitcnt vmcnt(0)" ::: "memory");
}

// ---------------- two-level fence-free grid barrier ------------------------
__device__ __forceinline__ void gridbar(int* cnts, int gen) {
  vmdrain();
  __syncthreads();
  if (threadIdx.x == 0) {
    int* gc = cnts + (blockIdx.x >> 4) * 64;
    int* root = cnts + 1024;
    int prev = __hip_atomic_fetch_add(gc, 1, __ATOMIC_RELAXED,
                                      __HIP_MEMORY_SCOPE_AGENT);
    if ((prev & 15) == 15)
      __hip_atomic_fetch_add(root, 1, __ATOMIC_RELAXED,
                             __HIP_MEMORY_SCOPE_AGENT);
    while (__hip_atomic_load(root, __ATOMIC_RELAXED,
                             __HIP_MEMORY_SCOPE_AGENT) < gen * 16) {
      __builtin_amdgcn_s_sleep(2);
    }
  }
  __syncthreads();
}

// ---------------- register-level 2-qubit gate ------------------------------
template <int NB, int HI, int LO>
__device__ __forceinline__ void gate2(float* x, const float* __restrict__ g) {
  constexpr int H = 1 << HI, L = 1 << LO, N = 1 << NB;
#pragma unroll
  for (int o = 0; o < N; ++o) {
    if (o & (H | L)) continue;
    float v0 = x[o], v1 = x[o + L], v2 = x[o + H], v3 = x[o + H + L];
    x[o]         = g[0]  * v0 + g[1]  * v1 + g[2]  * v2 + g[3]  * v3;
    x[o + L]     = g[4]  * v0 + g[5]  * v1 + g[6]  * v2 + g[7]  * v3;
    x[o + H]     = g[8]  * v0 + g[9]  * v1 + g[10] * v2 + g[11] * v3;
    x[o + H + L] = g[12] * v0 + g[13] * v1 + g[14] * v2 + g[15] * v3;
  }
}

template <int ST>
__device__ __forceinline__ void vxf(float* s, const float* __restrict__ g, int b) {
  float x[16];
#pragma unroll
  for (int m = 0; m < 16; ++m) x[m] = s[PAD(b + m * ST)];
  gate2<4, 3, 2>(x, g);
  gate2<4, 2, 1>(x, g);
  gate2<4, 1, 0>(x, g);
#pragma unroll
  for (int m = 0; m < 16; ++m) s[PAD(b + m * ST)] = x[m];
}

template <int B2, int B1, int B0>
__device__ __forceinline__ void bondpair(float* s, const float* __restrict__ g,
                                         int t) {
  constexpr int MASK = (1 << B2) | (1 << B1) | (1 << B0);
  int b = 0, rem = t;
#pragma unroll
  for (int p = 0; p < 12; ++p) {
    if (!((MASK >> p) & 1)) {
      b |= (rem & 1) << p;
      rem >>= 1;
    }
  }
  float x[8];
#pragma unroll
  for (int m = 0; m < 8; ++m) {
    int off = ((m >> 2) & 1) * (1 << B2) + ((m >> 1) & 1) * (1 << B1) +
              (m & 1) * (1 << B0);
    x[m] = s[PAD(b + off)];
  }
  gate2<3, 2, 1>(x, g);  // bond (B2, B1)
  gate2<3, 1, 0>(x, g);  // bond (B1, B0)
#pragma unroll
  for (int m = 0; m < 8; ++m) {
    int off = ((m >> 2) & 1) * (1 << B2) + ((m >> 1) & 1) * (1 << B1) +
              (m & 1) * (1 << B0);
    s[PAD(b + off)] = x[m];
  }
}

// ---------------------------------------------------------------------------
// Grid 256 x 512, plain launch. LDS 8224 floats (32.9KB).
// ---------------------------------------------------------------------------
__global__ __launch_bounds__(512) void k_all(const float* __restrict__ peps,
                                             const int* __restrict__ x,
                                             const float* __restrict__ gate,
                                             float* __restrict__ ws,
                                             float* __restrict__ out,
                                             int* __restrict__ cnt) {
  __shared__ float sm[8224];
  const int t = threadIdx.x;   // 0..511
  const int b = blockIdx.x;    // 0..255
  const int r3 = t & 255, half = t >> 8;
  float* psi = ws + PSIO;
  int gen = 0;

  // ===================== phase 1: column tensors ===========================
  if (b < 192) {
    float* p01 = sm;
    float* p23 = sm + 4096;
    int col = 1 + (b >> 6);
    int pb = b & 63;
#pragma unroll
    for (int k = 0; k < 8; ++k) {
      int e = k * 512 + t;
      int r12 = e & 15, l12 = (e >> 4) & 15, d2 = (e >> 8) & 3, p = e >> 10;
      int l1 = l12 >> 2, l2 = l12 & 3, r1 = r12 >> 2, r2 = r12 & 3;
      float s01 = 0.f, s23 = 0.f;
#pragma unroll
      for (int d = 0; d < 4; ++d) {
        s01 += peps[PIDX(0, col, (p >> 1), 0, d, l1, r1)] *
               peps[PIDX(1, col, (p & 1), d, d2, l2, r2)];
        s23 += peps[PIDX(2, col, (p >> 1), d2, d, l1, r1)] *
               peps[PIDX(3, col, (p & 1), d, 0, l2, r2)];
      }
      p01[e] = s01;
      p23[e] = s23;
    }
    __syncthreads();
    const int coloffs[3] = {COL1, COL2, COL3};
    float* outc = ws + coloffs[col - 1];
#pragma unroll
    for (int pp = 0; pp < 2; ++pp) {
      int part = pb * 2 + pp;
#pragma unroll
      for (int k = 0; k < 4; ++k) {
        int eq = part * 8192 + (k * 512 + t) * 4;
        int r34b = eq & 15;
        int r12 = (eq >> 4) & 15, l34 = (eq >> 8) & 15, l12 = (eq >> 12) & 15;
        int p = eq >> 16;
        int pa = p >> 2, pbv = p & 3;
        v4f acc = {0.f, 0.f, 0.f, 0.f};
#pragma unroll
        for (int d2 = 0; d2 < 4; ++d2) {
          float a01 = p01[((((pa * 4 + d2) << 4) | l12) << 4) | r12];
          const float4 b4 =
              *(const float4*)&p23[((((pbv * 4 + d2) << 4) | l34) << 4) | r34b];
          acc.x += a01 * b4.x;
          acc.y += a01 * b4.y;
          acc.z += a01 * b4.z;
          acc.w += a01 * b4.w;
        }
        cohstore(&outc[eq], acc);
      }
    }
  } else if (b < 194) {
    float* p01 = sm;
    float* p23 = sm + 4096;
    int col = (b == 192) ? 0 : 4;
    const int lsh = (col == 0) ? 0 : 2;
    const int rsh = (col == 4) ? 0 : 2;
    const int ldim = 1 << lsh, rdim = 1 << rsh;
    const int LLB = 2 * lsh, RRB = 2 * rsh;
    const int LL = 1 << LLB, RR = 1 << RRB;
    int n12 = (LL * RR) << 4;
    for (int e = t; e < n12; e += 512) {
      int r12 = e & (RR - 1);
      int l12 = (e >> RRB) & (LL - 1);
      int d2 = (e >> (RRB + LLB)) & 3;
      int p = e >> (RRB + LLB + 2);
      int l1 = l12 >> lsh, l2 = l12 & (ldim - 1);
      int r1 = r12 >> rsh, r2 = r12 & (rdim - 1);
      float s01 = 0.f, s23 = 0.f;
      for (int d = 0; d < 4; ++d) {
        s01 += peps[PIDX(0, col, (p >> 1), 0, d, l1, r1)] *
               peps[PIDX(1, col, (p & 1), d, d2, l2, r2)];
        s23 += peps[PIDX(2, col, (p >> 1), d2, d, l1, r1)] *
               peps[PIDX(3, col, (p & 1), d, 0, l2, r2)];
      }
      p01[e] = s01;
      p23[e] = s23;
    }
    __syncthreads();
    const int LB = 2 * LLB, RB = 2 * RRB;
    int total = 16 << (LB + RB);
    float* outc = ws + ((col == 0) ? COL0 : COL4);
    for (int e = t; e < total; e += 512) {
      int r = e & ((1 << RB) - 1);
      int l = (e >> RB) & ((1 << LB) - 1);
      int p = e >> (RB + LB);
      int r34 = r & (RR - 1), r12 = r >> RRB;
      int l34 = l & (LL - 1), l12 = l >> LLB;
      int pa = p >> 2, pbv = p & 3;
      float sacc = 0.f;
      for (int d2 = 0; d2 < 4; ++d2) {
        sacc += p01[((((pa * 4 + d2) << LLB) | l12) << RRB) | r12] *
                p23[((((pbv * 4 + d2) << LLB) | l34) << RRB) | r34];
      }
      cohstore1(&outc[e], sacc);
    }
  }
  gridbar(cnt, ++gen);

  // ============ phase 2: M34T (t<256) || M01 (t>=256, b<64) ================
  {
    float* c3buf = sm;           // [4112]
    float* c4buf = sm + 4112;    // [4112]
    const float* col3 = ws + COL3;
    const float* col4 = ws + COL4;
    const int L3 = b;
    if (t < 256) {
      float v3[16], v4[16];
#pragma unroll
      for (int k = 0; k < 16; ++k) {
        v4[k] = agl(&col4[k * 256 + t]);
        v3[k] = agl(&col3[k * 65536 + L3 * 256 + t]);
      }
#pragma unroll
      for (int k = 0; k < 16; ++k) {
        c4buf[k * 257 + t] = v4[k];
        c3buf[k * 257 + t] = v3[k];
      }
    } else if (b < 64) {
      // M01[(c0*16+c1)*256 + R2] = sum_R1 col0[c0,R1]*col1[c1,R1,R2]
      // r13 fix: col0/col1 reads now COHERENT (r7's only cached ws reads —
      // deterministic stale-zero source under the wbL2 model).
      int tt = t - 256;
      int c1 = b >> 2, q = b & 3;
      int r2l = tt & 63, c0g = tt >> 6;
      int R2 = q * 64 + r2l;
      const float* col0 = ws + COL0;
      const float* col1 = ws + COL1;
      float a0 = 0.f, a1 = 0.f, a2 = 0.f, a3 = 0.f;
      for (int R1 = 0; R1 < 256; ++R1) {
        float bv = agl(&col1[(c1 * 256 + R1) * 256 + R2]);
        a0 += agl(&col0[(c0g * 4 + 0) * 256 + R1]) * bv;
        a1 += agl(&col0[(c0g * 4 + 1) * 256 + R1]) * bv;
        a2 += agl(&col0[(c0g * 4 + 2) * 256 + R1]) * bv;
        a3 += agl(&col0[(c0g * 4 + 3) * 256 + R1]) * bv;
      }
      float* m01 = ws + M01TO;
      cohstore1(&m01[((c0g * 4 + 0) * 16 + c1) * 256 + R2], a0);
      cohstore1(&m01[((c0g * 4 + 1) * 16 + c1) * 256 + R2], a1);
      cohstore1(&m01[((c0g * 4 + 2) * 16 + c1) * 256 + R2], a2);
      cohstore1(&m01[((c0g * 4 + 3) * 16 + c1) * 256 + R2], a3);
    }
    __syncthreads();
    if (t < 256) {
      int c3 = t >> 4, c4 = t & 15;
      float acc = 0.f;
      for (int B = 0; B < 256; ++B)
        acc += c3buf[c3 * 257 + B] * c4buf[c4 * 257 + B];
      cohstore1(&(ws + M34TO)[L3 * 256 + t], acc);
    }
  }
  gridbar(cnt, ++gen);

  // ===================== phase 3: T012 = M01 x Col2 ========================
  {
    float* A = sm;  // [4096] = [i=16][R2=256]
    const float* m01 = ws + M01TO;
    const float* col2 = ws + COL2;
    float* t012p = ws + T12TO;
    int c2 = b & 15, tg = b >> 4;
    {
      float tmp[8];
#pragma unroll
      for (int k = 0; k < 2; ++k)
#pragma unroll
        for (int j = 0; j < 4; ++j)
          tmp[k * 4 + j] = agl(&m01[tg * 4096 + (k * 512 + t) * 4 + j]);
#pragma unroll
      for (int k = 0; k < 2; ++k)
#pragma unroll
        for (int j = 0; j < 4; ++j)
          A[(k * 512 + t) * 4 + j] = tmp[k * 4 + j];
    }
    __syncthreads();
    float acc[8] = {};
    const float* cbase = col2 + c2 * 65536 + r3;
    float cur[32], nxt[32];
#pragma unroll
    for (int j = 0; j < 32; ++j) cur[j] = agl(&cbase[j * 256]);
#pragma unroll
    for (int ch = 0; ch < 8; ++ch) {
      if (ch < 7) {
#pragma unroll
        for (int j = 0; j < 32; ++j)
          nxt[j] = agl(&cbase[((ch + 1) * 32 + j) * 256]);
      }
#pragma unroll
      for (int jj = 0; jj < 32; jj += 4) {
        int R2 = ch * 32 + jj;
#pragma unroll
        for (int i = 0; i < 8; ++i) {
          float4 a4 = *(const float4*)&A[(half * 8 + i) * 256 + R2];
          acc[i] += a4.x * cur[jj] + a4.y * cur[jj + 1] + a4.z * cur[jj + 2] +
                    a4.w * cur[jj + 3];
        }
      }
      if (ch < 7) {
#pragma unroll
        for (int j = 0; j < 32; ++j) cur[j] = nxt[j];
      }
    }
#pragma unroll
    for (int i = 0; i < 8; ++i)
      cohstore1(&t012p[c2 * 65536 + (tg * 16 + half * 8 + i) * 256 + r3],
                acc[i]);
  }
  gridbar(cnt, ++gen);

  // ===================== phase 4: psi = T012 x M34T (gate layout) ==========
  {
    float* A = sm;            // [4096] = [i=c2=16][L3=256]
    float* S = sm + 4096;     // [4112] = [c2=16][c34=257-padded]
    const float* t012p = ws + T12TO;
    const float* m34t = ws + M34TO;
    int tg = b;
    {
      float tmp[8];
#pragma unroll
      for (int i = 0; i < 8; ++i)
        tmp[i] = agl(&t012p[(half * 8 + i) * 65536 + tg * 256 + r3]);
#pragma unroll
      for (int i = 0; i < 8; ++i) A[(half * 8 + i) * 256 + r3] = tmp[i];
    }
    __syncthreads();
    float acc[8] = {};
    const float* mbase = m34t + r3;
    float cur[32], nxt[32];
#pragma unroll
    for (int j = 0; j < 32; ++j) cur[j] = agl(&mbase[j * 256]);
#pragma unroll
    for (int ch = 0; ch < 8; ++ch) {
      if (ch < 7) {
#pragma unroll
        for (int j = 0; j < 32; ++j)
          nxt[j] = agl(&mbase[((ch + 1) * 32 + j) * 256]);
      }
#pragma unroll
      for (int jj = 0; jj < 32; jj += 4) {
        int L3 = ch * 32 + jj;
#pragma unroll
        for (int i = 0; i < 8; ++i) {
          float4 a4 = *(const float4*)&A[(half * 8 + i) * 256 + L3];
          acc[i] += a4.x * cur[jj] + a4.y * cur[jj + 1] + a4.z * cur[jj + 2] +
                    a4.w * cur[jj + 3];
        }
      }
      if (ch < 7) {
#pragma unroll
        for (int j = 0; j < 32; ++j) cur[j] = nxt[j];
      }
    }
#pragma unroll
    for (int i = 0; i < 8; ++i) S[(half * 8 + i) * 257 + r3] = acc[i];
    __syncthreads();
    int c3 = r3 >> 4, c2 = r3 & 15;
    int base = c3 * 65536 + (tg >> 4) * 256 + (tg & 15) * 16 + c2;
#pragma unroll
    for (int vv = 0; vv < 8; ++vv) {
      int v = half * 8 + vv;
      cohstore1(&psi[base + v * 4096], S[c2 * 257 + c3 * 16 + v]);
    }
  }
  gridbar(cnt, ++gen);

  // ===================== gate loop: 5 x (P1, P2) ===========================
  float g[16];
#pragma unroll
  for (int i = 0; i < 16; ++i) g[i] = gate[i];
  float* s = sm;

  for (int it = 0; it < 5; ++it) {
    // ---- P1: G2_01, G2_12, M16_0, M16_1. slab = low 12 bits, o = b -------
    {
      int f0 = t * 4, f1 = (512 + t) * 4;
      v4f a, c;
      cohload2(psi + b * 4096 + f0, psi + b * 4096 + f1, a, c);
      *(v4f*)(s + PAD(f0)) = a;
      *(v4f*)(s + PAD(f1)) = c;
    }
    __syncthreads();
    bondpair<8, 4, 0>(s, g, t);
    __syncthreads();
    bondpair<9, 5, 1>(s, g, t);
    __syncthreads();
    bondpair<10, 6, 2>(s, g, t);
    __syncthreads();
    bondpair<11, 7, 3>(s, g, t);
    __syncthreads();
    if (t < 256) vxf<256>(s, g, t);                          // M16_0
    __syncthreads();
    if (t < 256) vxf<16>(s, g, ((t >> 4) << 8) | (t & 15));  // M16_1
    __syncthreads();
    {
      int f0 = t * 4, f1 = (512 + t) * 4;
      cohstore(psi + b * 4096 + f0, *(const v4f*)(s + PAD(f0)));
      cohstore(psi + b * 4096 + f1, *(const v4f*)(s + PAD(f1)));
    }
    gridbar(cnt, ++gen);

    // ---- P2: G2_23, G2_34, M16_2..4. slab = bits {19..12,3..0}, o = b ----
    {
      int f0 = t * 4, f1 = (512 + t) * 4;
      int a0 = (f0 >> 8) * 65536 + ((f0 >> 4) & 15) * 4096 + b * 16 + (f0 & 15);
      int a1 = (f1 >> 8) * 65536 + ((f1 >> 4) & 15) * 4096 + b * 16 + (f1 & 15);
      v4f a, c;
      cohload2(psi + a0, psi + a1, a, c);
      *(v4f*)(s + PAD(f0)) = a;
      *(v4f*)(s + PAD(f1)) = c;
    }
    __syncthreads();
    bondpair<0, 8, 4>(s, g, t);
    __syncthreads();
    bondpair<1, 9, 5>(s, g, t);
    __syncthreads();
    bondpair<2, 10, 6>(s, g, t);
    __syncthreads();
    bondpair<3, 11, 7>(s, g, t);
    __syncthreads();
    if (t < 256) vxf<1>(s, g, t * 16);                       // M16_2
    __syncthreads();
    if (t < 256) vxf<256>(s, g, t);                          // M16_3
    __syncthreads();
    if (t < 256) vxf<16>(s, g, ((t >> 4) << 8) | (t & 15));  // M16_4
    __syncthreads();
    if (it == 4) {
      if (t < 64) {
        int idx = 0;
#pragma unroll
        for (int q = 0; q < 20; ++q) {
          int i = q / 5, j = q % 5;
          int pos = (j == 0) ? (11 - i)
                   : (j == 1) ? (7 - i)
                   : (j == 2) ? (3 - i)
                   : (j == 3) ? (19 - i)
                              : (15 - i);
          idx |= x[t * 20 + q] << pos;
        }
        if (((idx >> 4) & 255) == b) {
          int local = ((idx >> 16) & 15) * 256 + ((idx >> 12) & 15) * 16 +
                      (idx & 15);
          out[t] = s[PAD(local)];
        }
      }
    } else {
      int f0 = t * 4, f1 = (512 + t) * 4;
      int a0 = (f0 >> 8) * 65536 + ((f0 >> 4) & 15) * 4096 + b * 16 + (f0 & 15);
      int a1 = (f1 >> 8) * 65536 + ((f1 >> 4) & 15) * 4096 + b * 16 + (f1 & 15);
      cohstore(psi + a0, *(const v4f*)(s + PAD(f0)));
      cohstore(psi + a1, *(const v4f*)(s + PAD(f1)));
      gridbar(cnt, ++gen);
    }
  }
}

// ---------------------------------------------------------------------------
extern "C" void kernel_launch(void* const* d_in, const int* in_sizes, int n_in,
                              void* d_out, int out_size, void* d_ws, size_t ws_size,
                              hipStream_t stream) {
  const int* x = (const int*)d_in[0];
  const float* peps = (const float*)d_in[1];
  const float* gate = (const float*)d_in[2];
  float* ws = (float*)d_ws;
  float* out = (float*)d_out;
  int* cnt = (int*)(ws + CNTO);

  // zero the barrier tree (graph-capturable async memset node)
  hipMemsetAsync((void*)cnt, 0, 1088 * sizeof(int), stream);

  k_all<<<256, 512, 0, stream>>>(peps, x, gate, ws, out, cnt);
}

// Round 14
// 210.265 us; speedup vs baseline: 1.0117x; 1.0117x over previous
//
#include <hip/hip_runtime.h>

// ---------------------------------------------------------------------------
// PEPS 4x5, D=4, P=2, depth-5 gate sweeps, 64-point gather.
// ONE persistent kernel (plain launch), 13 fence-free tree barriers:
//   P1 cols -> P2 {M34T || M01} -> P3 t012 -> P4 psi0 -> 5x(G-P1, G-P2).
//
// FINAL coherence model (r6..r13 arc resolved): coherent (sc0 sc1) stores
// invalidate/update stale L2 lines on their way to the coherent point, so
// CACHED reads of coherently-written ws data are SAFE (r7's cached M01
// reads were correct to rounding). Cached WRITES remain unsafe cross-XCD
// (dirty-L2 invisibility) -> all ws stores stay sc0 sc1; psi loads in the
// gate loop stay coherent (re-read across XCDs every phase). The r6/r11-13
// absmax differences were deterministic fp32 summation-order rounding
// (quantized at ~1 bf16 ulp of the max output element; threshold ~4.75
// ulps), NOT memory corruption — except r11/r12 (real bug, abandoned).
//
// r14 = r7 byte-exact (best verified: 200.2us, absmax 4.427219e+20
// deterministic-pass). Consolidation round after r8-r13 experiments all
// came back slower or wrong.
// Gate layout: psi idx = c3<<16 | c4<<12 | c0<<8 | c1<<4 | c2.
// ---------------------------------------------------------------------------

#define PAD(i) ((i) + (((i) >> 4) << 2))   // +4 floats per 16 -> LDS bank spread
#define PIDX(i,j,p,u,d,l,r) (((((((i)*5+(j))*2+(p))*4+(u))*4+(d))*4+(l))*4+(r))

typedef float v4f __attribute__((ext_vector_type(4)));

// workspace float offsets
static constexpr int COL0  = 0;                    // [16][256]
static constexpr int COL1  = 4096;                 // [16][256][256]
static constexpr int COL2  = COL1 + 1048576;
static constexpr int COL3  = COL2 + 1048576;
static constexpr int COL4  = COL3 + 1048576;       // [16][256]
static constexpr int M01TO = COL4 + 4096;          // [c01=256][R2=256]
static constexpr int M34TO = M01TO + 65536;        // [L3=256][c34=256]
static constexpr int T12TO = M34TO + 65536;        // [c2=16][c01=256][R3=256]
static constexpr int PSIO  = T12TO + 1048576;      // [2^20] gate layout
static constexpr int CNTO  = PSIO + 1048576;       // barrier tree: 1088 ints

// ---------------- coherent-point access ------------------------------------
__device__ __forceinline__ float agl(const float* p) {      // coherent load
  return __hip_atomic_load(p, __ATOMIC_RELAXED, __HIP_MEMORY_SCOPE_AGENT);
}
__device__ __forceinline__ void cohload2(const float* p0, const float* p1,
                                         v4f& a, v4f& b) {
  asm volatile(
      "global_load_dwordx4 %0, %2, off sc0 sc1\n\t"
      "global_load_dwordx4 %1, %3, off sc0 sc1\n\t"
      "s_waitcnt vmcnt(0)"
      : "=&v"(a), "=&v"(b)
      : "v"(p0), "v"(p1)
      : "memory");
}
__device__ __forceinline__ void cohstore(float* p, v4f v) {
  asm volatile("global_store_dwordx4 %0, %1, off sc0 sc1"
               :
               : "v"(p), "v"(v)
               : "memory");
}
__device__ __forceinline__ void cohstore1(float* p, float v) {
  asm volatile("global_store_dword %0, %1, off sc0 sc1"
               :
               : "v"(p), "v"(v)
               : "memory");
}
__device__ __forceinline__ void vmdrain() {
  asm volatile("s_waitcnt vmcnt(0)" ::: "memory");
}

// ---------------- two-level fence-free grid barrier ------------------------
__device__ __forceinline__ void gridbar(int* cnts, int gen) {
  vmdrain();
  __syncthreads();
  if (threadIdx.x == 0) {
    int* gc = cnts + (blockIdx.x >> 4) * 64;
    int* root = cnts + 1024;
    int prev = __hip_atomic_fetch_add(gc, 1, __ATOMIC_RELAXED,
                                      __HIP_MEMORY_SCOPE_AGENT);
    if ((prev & 15) == 15)
      __hip_atomic_fetch_add(root, 1, __ATOMIC_RELAXED,
                             __HIP_MEMORY_SCOPE_AGENT);
    while (__hip_atomic_load(root, __ATOMIC_RELAXED,
                             __HIP_MEMORY_SCOPE_AGENT) < gen * 16) {
      __builtin_amdgcn_s_sleep(2);
    }
  }
  __syncthreads();
}

// ---------------- register-level 2-qubit gate ------------------------------
template <int NB, int HI, int LO>
__device__ __forceinline__ void gate2(float* x, const float* __restrict__ g) {
  constexpr int H = 1 << HI, L = 1 << LO, N = 1 << NB;
#pragma unroll
  for (int o = 0; o < N; ++o) {
    if (o & (H | L)) continue;
    float v0 = x[o], v1 = x[o + L], v2 = x[o + H], v3 = x[o + H + L];
    x[o]         = g[0]  * v0 + g[1]  * v1 + g[2]  * v2 + g[3]  * v3;
    x[o + L]     = g[4]  * v0 + g[5]  * v1 + g[6]  * v2 + g[7]  * v3;
    x[o + H]     = g[8]  * v0 + g[9]  * v1 + g[10] * v2 + g[11] * v3;
    x[o + H + L] = g[12] * v0 + g[13] * v1 + g[14] * v2 + g[15] * v3;
  }
}

template <int ST>
__device__ __forceinline__ void vxf(float* s, const float* __restrict__ g, int b) {
  float x[16];
#pragma unroll
  for (int m = 0; m < 16; ++m) x[m] = s[PAD(b + m * ST)];
  gate2<4, 3, 2>(x, g);
  gate2<4, 2, 1>(x, g);
  gate2<4, 1, 0>(x, g);
#pragma unroll
  for (int m = 0; m < 16; ++m) s[PAD(b + m * ST)] = x[m];
}

template <int B2, int B1, int B0>
__device__ __forceinline__ void bondpair(float* s, const float* __restrict__ g,
                                         int t) {
  constexpr int MASK = (1 << B2) | (1 << B1) | (1 << B0);
  int b = 0, rem = t;
#pragma unroll
  for (int p = 0; p < 12; ++p) {
    if (!((MASK >> p) & 1)) {
      b |= (rem & 1) << p;
      rem >>= 1;
    }
  }
  float x[8];
#pragma unroll
  for (int m = 0; m < 8; ++m) {
    int off = ((m >> 2) & 1) * (1 << B2) + ((m >> 1) & 1) * (1 << B1) +
              (m & 1) * (1 << B0);
    x[m] = s[PAD(b + off)];
  }
  gate2<3, 2, 1>(x, g);  // bond (B2, B1)
  gate2<3, 1, 0>(x, g);  // bond (B1, B0)
#pragma unroll
  for (int m = 0; m < 8; ++m) {
    int off = ((m >> 2) & 1) * (1 << B2) + ((m >> 1) & 1) * (1 << B1) +
              (m & 1) * (1 << B0);
    s[PAD(b + off)] = x[m];
  }
}

// ---------------------------------------------------------------------------
// Grid 256 x 512, plain launch. LDS 8224 floats (32.9KB).
// ---------------------------------------------------------------------------
__global__ __launch_bounds__(512) void k_all(const float* __restrict__ peps,
                                             const int* __restrict__ x,
                                             const float* __restrict__ gate,
                                             float* __restrict__ ws,
                                             float* __restrict__ out,
                                             int* __restrict__ cnt) {
  __shared__ float sm[8224];
  const int t = threadIdx.x;   // 0..511
  const int b = blockIdx.x;    // 0..255
  const int r3 = t & 255, half = t >> 8;
  float* psi = ws + PSIO;
  int gen = 0;

  // ===================== phase 1: column tensors ===========================
  if (b < 192) {
    float* p01 = sm;
    float* p23 = sm + 4096;
    int col = 1 + (b >> 6);
    int pb = b & 63;
#pragma unroll
    for (int k = 0; k < 8; ++k) {
      int e = k * 512 + t;
      int r12 = e & 15, l12 = (e >> 4) & 15, d2 = (e >> 8) & 3, p = e >> 10;
      int l1 = l12 >> 2, l2 = l12 & 3, r1 = r12 >> 2, r2 = r12 & 3;
      float s01 = 0.f, s23 = 0.f;
#pragma unroll
      for (int d = 0; d < 4; ++d) {
        s01 += peps[PIDX(0, col, (p >> 1), 0, d, l1, r1)] *
               peps[PIDX(1, col, (p & 1), d, d2, l2, r2)];
        s23 += peps[PIDX(2, col, (p >> 1), d2, d, l1, r1)] *
               peps[PIDX(3, col, (p & 1), d, 0, l2, r2)];
      }
      p01[e] = s01;
      p23[e] = s23;
    }
    __syncthreads();
    const int coloffs[3] = {COL1, COL2, COL3};
    float* outc = ws + coloffs[col - 1];
#pragma unroll
    for (int pp = 0; pp < 2; ++pp) {
      int part = pb * 2 + pp;
#pragma unroll
      for (int k = 0; k < 4; ++k) {
        int eq = part * 8192 + (k * 512 + t) * 4;
        int r34b = eq & 15;
        int r12 = (eq >> 4) & 15, l34 = (eq >> 8) & 15, l12 = (eq >> 12) & 15;
        int p = eq >> 16;
        int pa = p >> 2, pbv = p & 3;
        v4f acc = {0.f, 0.f, 0.f, 0.f};
#pragma unroll
        for (int d2 = 0; d2 < 4; ++d2) {
          float a01 = p01[((((pa * 4 + d2) << 4) | l12) << 4) | r12];
          const float4 b4 =
              *(const float4*)&p23[((((pbv * 4 + d2) << 4) | l34) << 4) | r34b];
          acc.x += a01 * b4.x;
          acc.y += a01 * b4.y;
          acc.z += a01 * b4.z;
          acc.w += a01 * b4.w;
        }
        cohstore(&outc[eq], acc);
      }
    }
  } else if (b < 194) {
    float* p01 = sm;
    float* p23 = sm + 4096;
    int col = (b == 192) ? 0 : 4;
    const int lsh = (col == 0) ? 0 : 2;
    const int rsh = (col == 4) ? 0 : 2;
    const int ldim = 1 << lsh, rdim = 1 << rsh;
    const int LLB = 2 * lsh, RRB = 2 * rsh;
    const int LL = 1 << LLB, RR = 1 << RRB;
    int n12 = (LL * RR) << 4;
    for (int e = t; e < n12; e += 512) {
      int r12 = e & (RR - 1);
      int l12 = (e >> RRB) & (LL - 1);
      int d2 = (e >> (RRB + LLB)) & 3;
      int p = e >> (RRB + LLB + 2);
      int l1 = l12 >> lsh, l2 = l12 & (ldim - 1);
      int r1 = r12 >> rsh, r2 = r12 & (rdim - 1);
      float s01 = 0.f, s23 = 0.f;
      for (int d = 0; d < 4; ++d) {
        s01 += peps[PIDX(0, col, (p >> 1), 0, d, l1, r1)] *
               peps[PIDX(1, col, (p & 1), d, d2, l2, r2)];
        s23 += peps[PIDX(2, col, (p >> 1), d2, d, l1, r1)] *
               peps[PIDX(3, col, (p & 1), d, 0, l2, r2)];
      }
      p01[e] = s01;
      p23[e] = s23;
    }
    __syncthreads();
    const int LB = 2 * LLB, RB = 2 * RRB;
    int total = 16 << (LB + RB);
    float* outc = ws + ((col == 0) ? COL0 : COL4);
    for (int e = t; e < total; e += 512) {
      int r = e & ((1 << RB) - 1);
      int l = (e >> RB) & ((1 << LB) - 1);
      int p = e >> (RB + LB);
      int r34 = r & (RR - 1), r12 = r >> RRB;
      int l34 = l & (LL - 1), l12 = l >> LLB;
      int pa = p >> 2, pbv = p & 3;
      float sacc = 0.f;
      for (int d2 = 0; d2 < 4; ++d2) {
        sacc += p01[((((pa * 4 + d2) << LLB) | l12) << RRB) | r12] *
                p23[((((pbv * 4 + d2) << LLB) | l34) << RRB) | r34];
      }
      cohstore1(&outc[e], sacc);
    }
  }
  gridbar(cnt, ++gen);

  // ============ phase 2: M34T (t<256) || M01 (t>=256, b<64) ================
  {
    float* c3buf = sm;           // [4112]
    float* c4buf = sm + 4112;    // [4112]
    const float* col3 = ws + COL3;
    const float* col4 = ws + COL4;
    const int L3 = b;
    if (t < 256) {
      float v3[16], v4[16];
#pragma unroll
      for (int k = 0; k < 16; ++k) {
        v4[k] = agl(&col4[k * 256 + t]);
        v3[k] = agl(&col3[k * 65536 + L3 * 256 + t]);
      }
#pragma unroll
      for (int k = 0; k < 16; ++k) {
        c4buf[k * 257 + t] = v4[k];
        c3buf[k * 257 + t] = v3[k];
      }
    } else if (b < 64) {
      // M01[(c0*16+c1)*256 + R2] = sum_R1 col0[c0,R1]*col1[c1,R1,R2]
      // cached col0/col1 reads: safe (coherent stores invalidated stale L2;
      // verified deterministic-correct in r7/r8).
      int tt = t - 256;
      int c1 = b >> 2, q = b & 3;
      int r2l = tt & 63, c0g = tt >> 6;
      int R2 = q * 64 + r2l;
      const float* col0 = ws + COL0;
      const float* col1 = ws + COL1;
      float a0 = 0.f, a1 = 0.f, a2 = 0.f, a3 = 0.f;
      for (int R1 = 0; R1 < 256; ++R1) {
        float bv = col1[(c1 * 256 + R1) * 256 + R2];
        a0 += col0[(c0g * 4 + 0) * 256 + R1] * bv;
        a1 += col0[(c0g * 4 + 1) * 256 + R1] * bv;
        a2 += col0[(c0g * 4 + 2) * 256 + R1] * bv;
        a3 += col0[(c0g * 4 + 3) * 256 + R1] * bv;
      }
      float* m01 = ws + M01TO;
      cohstore1(&m01[((c0g * 4 + 0) * 16 + c1) * 256 + R2], a0);
      cohstore1(&m01[((c0g * 4 + 1) * 16 + c1) * 256 + R2], a1);
      cohstore1(&m01[((c0g * 4 + 2) * 16 + c1) * 256 + R2], a2);
      cohstore1(&m01[((c0g * 4 + 3) * 16 + c1) * 256 + R2], a3);
    }
    __syncthreads();
    if (t < 256) {
      int c3 = t >> 4, c4 = t & 15;
      float acc = 0.f;
      for (int B = 0; B < 256; ++B)
        acc += c3buf[c3 * 257 + B] * c4buf[c4 * 257 + B];
      cohstore1(&(ws + M34TO)[L3 * 256 + t], acc);
    }
  }
  gridbar(cnt, ++gen);

  // ===================== phase 3: T012 = M01 x Col2 ========================
  {
    float* A = sm;  // [4096] = [i=16][R2=256]
    const float* m01 = ws + M01TO;
    const float* col2 = ws + COL2;
    float* t012p = ws + T12TO;
    int c2 = b & 15, tg = b >> 4;
    {
      float tmp[8];
#pragma unroll
      for (int k = 0; k < 2; ++k)
#pragma unroll
        for (int j = 0; j < 4; ++j)
          tmp[k * 4 + j] = agl(&m01[tg * 4096 + (k * 512 + t) * 4 + j]);
#pragma unroll
      for (int k = 0; k < 2; ++k)
#pragma unroll
        for (int j = 0; j < 4; ++j)
          A[(k * 512 + t) * 4 + j] = tmp[k * 4 + j];
    }
    __syncthreads();
    float acc[8] = {};
    const float* cbase = col2 + c2 * 65536 + r3;
    float cur[32], nxt[32];
#pragma unroll
    for (int j = 0; j < 32; ++j) cur[j] = agl(&cbase[j * 256]);
#pragma unroll
    for (int ch = 0; ch < 8; ++ch) {
      if (ch < 7) {
#pragma unroll
        for (int j = 0; j < 32; ++j)
          nxt[j] = agl(&cbase[((ch + 1) * 32 + j) * 256]);
      }
#pragma unroll
      for (int jj = 0; jj < 32; jj += 4) {
        int R2 = ch * 32 + jj;
#pragma unroll
        for (int i = 0; i < 8; ++i) {
          float4 a4 = *(const float4*)&A[(half * 8 + i) * 256 + R2];
          acc[i] += a4.x * cur[jj] + a4.y * cur[jj + 1] + a4.z * cur[jj + 2] +
                    a4.w * cur[jj + 3];
        }
      }
      if (ch < 7) {
#pragma unroll
        for (int j = 0; j < 32; ++j) cur[j] = nxt[j];
      }
    }
#pragma unroll
    for (int i = 0; i < 8; ++i)
      cohstore1(&t012p[c2 * 65536 + (tg * 16 + half * 8 + i) * 256 + r3],
                acc[i]);
  }
  gridbar(cnt, ++gen);

  // ===================== phase 4: psi = T012 x M34T (gate layout) ==========
  {
    float* A = sm;            // [4096] = [i=c2=16][L3=256]
    float* S = sm + 4096;     // [4112] = [c2=16][c34=257-padded]
    const float* t012p = ws + T12TO;
    const float* m34t = ws + M34TO;
    int tg = b;
    {
      float tmp[8];
#pragma unroll
      for (int i = 0; i < 8; ++i)
        tmp[i] = agl(&t012p[(half * 8 + i) * 65536 + tg * 256 + r3]);
#pragma unroll
      for (int i = 0; i < 8; ++i) A[(half * 8 + i) * 256 + r3] = tmp[i];
    }
    __syncthreads();
    float acc[8] = {};
    const float* mbase = m34t + r3;
    float cur[32], nxt[32];
#pragma unroll
    for (int j = 0; j < 32; ++j) cur[j] = agl(&mbase[j * 256]);
#pragma unroll
    for (int ch = 0; ch < 8; ++ch) {
      if (ch < 7) {
#pragma unroll
        for (int j = 0; j < 32; ++j)
          nxt[j] = agl(&mbase[((ch + 1) * 32 + j) * 256]);
      }
#pragma unroll
      for (int jj = 0; jj < 32; jj += 4) {
        int L3 = ch * 32 + jj;
#pragma unroll
        for (int i = 0; i < 8; ++i) {
          float4 a4 = *(const float4*)&A[(half * 8 + i) * 256 + L3];
          acc[i] += a4.x * cur[jj] + a4.y * cur[jj + 1] + a4.z * cur[jj + 2] +
                    a4.w * cur[jj + 3];
        }
      }
      if (ch < 7) {
#pragma unroll
        for (int j = 0; j < 32; ++j) cur[j] = nxt[j];
      }
    }
#pragma unroll
    for (int i = 0; i < 8; ++i) S[(half * 8 + i) * 257 + r3] = acc[i];
    __syncthreads();
    int c3 = r3 >> 4, c2 = r3 & 15;
    int base = c3 * 65536 + (tg >> 4) * 256 + (tg & 15) * 16 + c2;
#pragma unroll
    for (int vv = 0; vv < 8; ++vv) {
      int v = half * 8 + vv;
      cohstore1(&psi[base + v * 4096], S[c2 * 257 + c3 * 16 + v]);
    }
  }
  gridbar(cnt, ++gen);

  // ===================== gate loop: 5 x (P1, P2) ===========================
  float g[16];
#pragma unroll
  for (int i = 0; i < 16; ++i) g[i] = gate[i];
  float* s = sm;

  for (int it = 0; it < 5; ++it) {
    // ---- P1: G2_01, G2_12, M16_0, M16_1. slab = low 12 bits, o = b -------
    {
      int f0 = t * 4, f1 = (512 + t) * 4;
      v4f a, c;
      cohload2(psi + b * 4096 + f0, psi + b * 4096 + f1, a, c);
      *(v4f*)(s + PAD(f0)) = a;
      *(v4f*)(s + PAD(f1)) = c;
    }
    __syncthreads();
    bondpair<8, 4, 0>(s, g, t);
    __syncthreads();
    bondpair<9, 5, 1>(s, g, t);
    __syncthreads();
    bondpair<10, 6, 2>(s, g, t);
    __syncthreads();
    bondpair<11, 7, 3>(s, g, t);
    __syncthreads();
    if (t < 256) vxf<256>(s, g, t);                          // M16_0
    __syncthreads();
    if (t < 256) vxf<16>(s, g, ((t >> 4) << 8) | (t & 15));  // M16_1
    __syncthreads();
    {
      int f0 = t * 4, f1 = (512 + t) * 4;
      cohstore(psi + b * 4096 + f0, *(const v4f*)(s + PAD(f0)));
      cohstore(psi + b * 4096 + f1, *(const v4f*)(s + PAD(f1)));
    }
    gridbar(cnt, ++gen);

    // ---- P2: G2_23, G2_34, M16_2..4. slab = bits {19..12,3..0}, o = b ----
    {
      int f0 = t * 4, f1 = (512 + t) * 4;
      int a0 = (f0 >> 8) * 65536 + ((f0 >> 4) & 15) * 4096 + b * 16 + (f0 & 15);
      int a1 = (f1 >> 8) * 65536 + ((f1 >> 4) & 15) * 4096 + b * 16 + (f1 & 15);
      v4f a, c;
      cohload2(psi + a0, psi + a1, a, c);
      *(v4f*)(s + PAD(f0)) = a;
      *(v4f*)(s + PAD(f1)) = c;
    }
    __syncthreads();
    bondpair<0, 8, 4>(s, g, t);
    __syncthreads();
    bondpair<1, 9, 5>(s, g, t);
    __syncthreads();
    bondpair<2, 10, 6>(s, g, t);
    __syncthreads();
    bondpair<3, 11, 7>(s, g, t);
    __syncthreads();
    if (t < 256) vxf<1>(s, g, t * 16);                       // M16_2
    __syncthreads();
    if (t < 256) vxf<256>(s, g, t);                          // M16_3
    __syncthreads();
    if (t < 256) vxf<16>(s, g, ((t >> 4) << 8) | (t & 15));  // M16_4
    __syncthreads();
    if (it == 4) {
      if (t < 64) {
        int idx = 0;
#pragma unroll
        for (int q = 0; q < 20; ++q) {
          int i = q / 5, j = q % 5;
          int pos = (j == 0) ? (11 - i)
                   : (j == 1) ? (7 - i)
                   : (j == 2) ? (3 - i)
                   : (j == 3) ? (19 - i)
                              : (15 - i);
          idx |= x[t * 20 + q] << pos;
        }
        if (((idx >> 4) & 255) == b) {
          int local = ((idx >> 16) & 15) * 256 + ((idx >> 12) & 15) * 16 +
                      (idx & 15);
          out[t] = s[PAD(local)];
        }
      }
    } else {
      int f0 = t * 4, f1 = (512 + t) * 4;
      int a0 = (f0 >> 8) * 65536 + ((f0 >> 4) & 15) * 4096 + b * 16 + (f0 & 15);
      int a1 = (f1 >> 8) * 65536 + ((f1 >> 4) & 15) * 4096 + b * 16 + (f1 & 15);
      cohstore(psi + a0, *(const v4f*)(s + PAD(f0)));
      cohstore(psi + a1, *(const v4f*)(s + PAD(f1)));
      gridbar(cnt, ++gen);
    }
  }
}

// ---------------------------------------------------------------------------
extern "C" void kernel_launch(void* const* d_in, const int* in_sizes, int n_in,
                              void* d_out, int out_size, void* d_ws, size_t ws_size,
                              hipStream_t stream) {
  const int* x = (const int*)d_in[0];
  const float* peps = (const float*)d_in[1];
  const float* gate = (const float*)d_in[2];
  float* ws = (float*)d_ws;
  float* out = (float*)d_out;
  int* cnt = (int*)(ws + CNTO);

  // zero the barrier tree (graph-capturable async memset node)
  hipMemsetAsync((void*)cnt, 0, 1088 * sizeof(int), stream);

  k_all<<<256, 512, 0, stream>>>(peps, x, gate, ws, out, cnt);
}